// Round 13
// baseline (1458.251 us; speedup 1.0000x reference)
//
#include <hip/hip_runtime.h>
#include <stdint.h>

// LTC encoder B=256,T=1024,F=64,H=128. One WG (1024 thr, 16 waves) per batch row.
// R12 post-mortem: weights resident (VGPR 64, pins held) yet dur unchanged ->
// bottleneck is the per-iter serial skeleton: 2 barrier-separated LDS round trips
// (~3150 cyc/iter invariant across all designs). R13: ONE barrier per step via
// consumer-side LN: producer publishes y=g.hc + raw wave stats pre-barrier;
// consumer folds normalization into the dot algebraically:
//   dot(W,hn) = rstd*dot(W,y) - rstd*mu*dot(W,g) + dot(W,be)
// with dot(W,g), dot(W,be) precomputed at init. y/part double-buffered.

#define B_ 256
#define T_ 1024
#define F_ 64
#define H_ 128
#define EPS_ 1e-5f
#define NT_ 1024

typedef _Float16 h2 __attribute__((ext_vector_type(2)));
typedef __fp16  f16v2 __attribute__((ext_vector_type(2)));

__device__ __forceinline__ h2 pkf16(float a, float b) {
  union { f16v2 f; h2 h; } c; c.f = __builtin_amdgcn_cvt_pkrtz(a, b); return c.h;
}
__device__ __forceinline__ h2 as_h2(uint32_t u) { union { uint32_t u; h2 h; } c; c.u = u; return c.h; }
__device__ __forceinline__ uint32_t as_u32(h2 h) { union { h2 h; uint32_t u; } c; c.h = h; return c.u; }

#if __has_builtin(__builtin_amdgcn_fdot2)
__device__ __forceinline__ float fdot2(h2 a, h2 b, float c) { return __builtin_amdgcn_fdot2(a, b, c, false); }
#else
__device__ __forceinline__ float fdot2(h2 a, h2 b, float c) { return c + (float)a.x*(float)b.x + (float)a.y*(float)b.y; }
#endif

__device__ __forceinline__ float tanh_fast(float a) {
  float aa = fabsf(a);
  float e  = __expf(2.f * aa);
  float th = 1.f - 2.f / (e + 1.f);
  return copysignf(th, a);
}
__device__ __forceinline__ float softplus_fast(float x) {
  return (x > 20.f) ? x : __logf(1.f + __expf(x));
}

#define DPP_ADD(VV_, CTRL_) { int dt_ = __builtin_amdgcn_update_dpp(0, __float_as_int(VV_), (CTRL_), 0xF, 0xF, true); (VV_) += __int_as_float(dt_); }
#define QSUM(VV_) DPP_ADD(VV_, 0xB1) DPP_ADD(VV_, 0x4E)
#define WRED(VV_) { DPP_ADD(VV_, 0x124) DPP_ADD(VV_, 0x128) DPP_ADD(VV_, 0x142) DPP_ADD(VV_, 0x143) \
  (VV_) = __int_as_float(__builtin_amdgcn_readlane(__float_as_int(VV_), 63)); }

#define PACKW(DST_, SRC_, N4_) { const float4* p_ = (const float4*)(SRC_); \
  _Pragma("unroll") \
  for (int ii_ = 0; ii_ < (N4_); ++ii_) { float4 v_ = p_[ii_]; \
    DST_[2*ii_] = as_u32(pkf16(v_.x, v_.y)); DST_[2*ii_+1] = as_u32(pkf16(v_.z, v_.w)); } }

#define PINA(ARR_, N_) { _Pragma("unroll") \
  for (int ii_ = 0; ii_ < (N_); ++ii_) asm volatile("" : "+v"(ARR_[ii_])); }

#define LOADHV(HV_, SRC_) { const uint4* p_ = (const uint4*)(SRC_); \
  uint4 a_ = p_[0], b_ = p_[1], c_ = p_[2], d_ = p_[3]; \
  HV_[0]=as_h2(a_.x); HV_[1]=as_h2(a_.y); HV_[2]=as_h2(a_.z); HV_[3]=as_h2(a_.w); \
  HV_[4]=as_h2(b_.x); HV_[5]=as_h2(b_.y); HV_[6]=as_h2(b_.z); HV_[7]=as_h2(b_.w); \
  HV_[8]=as_h2(c_.x); HV_[9]=as_h2(c_.y); HV_[10]=as_h2(c_.z); HV_[11]=as_h2(c_.w); \
  HV_[12]=as_h2(d_.x); HV_[13]=as_h2(d_.y); HV_[14]=as_h2(d_.z); HV_[15]=as_h2(d_.w); }

// full-dot constant: dot(pinned weight quarter, f32 vector quarter) -> quad-uniform
__device__ __forceinline__ float constdot(const uint32_t* ww, const float* vseg) {
  float c = 0.f;
  const float4* p = (const float4*)vseg;
  #pragma unroll
  for (int ii = 0; ii < 8; ++ii) {
    float4 v = p[ii];
    c = fdot2(as_h2(ww[2*ii]),     pkf16(v.x, v.y), c);
    c = fdot2(as_h2(ww[2*ii+1]),   pkf16(v.z, v.w), c);
  }
  QSUM(c)
  return c;
}

__global__ void __launch_bounds__(NT_, 4) ltc_scan(
    const float* __restrict__ x,
    const float* __restrict__ Wh0, const float* __restrict__ bh0,
    const float* __restrict__ Wx0, const float* __restrict__ bx0,
    const float* __restrict__ Wt0, const float* __restrict__ bt0,
    const float* __restrict__ tau0, const float* __restrict__ g0,
    const float* __restrict__ be0,
    const float* __restrict__ Wh1, const float* __restrict__ bh1,
    const float* __restrict__ Wx1, const float* __restrict__ bx1,
    const float* __restrict__ Wt1, const float* __restrict__ bt1,
    const float* __restrict__ tau1, const float* __restrict__ g1,
    const float* __restrict__ be1,
    float* __restrict__ out)
{
  __shared__ __align__(16) uint32_t xs[2][2048];   // x chunks: 64 steps x 32 dwords
  __shared__ __align__(16) uint32_t y0p[2][64];    // g0.hc0 packed f16, dbuf
  __shared__ __align__(16) uint32_t y1p[2][64];    // g1.hc1 packed f16, dbuf
  __shared__ __align__(16) float2   part[2][16];   // raw wave stats (s, s2), dbuf

  const int t     = threadIdx.x;
  const int q     = t & 3;
  const int j     = (t >> 2) & 127;
  const int layer = t >> 9;
  const int w     = t >> 6;
  const int l     = t & 63;
  const int b     = blockIdx.x;

  if (t < 64) { y0p[0][t] = 0u; y0p[1][t] = 0u; y1p[0][t] = 0u; y1p[1][t] = 0u; }
  if (t < 32) ((float2*)part)[t] = make_float2(0.f, 0.f);

  // ---- pinned packed-f16 weights + fold constants ----
  uint32_t wA[16], wX[16], wT[16];
  float cgA, cbA, cgX, cbX, cgT, cbT;
  if (layer == 0) {
    PACKW(wA, Wh0 + j * H_ + q * 32, 8)
    PACKW(wX, Wx0 + j * F_ + q * 16, 4)
    PACKW(wT, Wt0 + j * F_ + q * 16, 4)
    PINA(wA, 16) PINA(wX, 8) PINA(wT, 8)
    cgA = constdot(wA, g0 + q * 32); cbA = constdot(wA, be0 + q * 32);
    cgX = 0.f; cbX = 0.f; cgT = 0.f; cbT = 0.f;
  } else {
    PACKW(wA, Wh1 + j * H_ + q * 32, 8)
    PACKW(wX, Wx1 + j * H_ + q * 32, 8)
    PACKW(wT, Wt1 + j * H_ + q * 32, 8)
    PINA(wA, 16) PINA(wX, 16) PINA(wT, 16)
    cgA = constdot(wA, g1 + q * 32); cbA = constdot(wA, be1 + q * 32);
    cgX = constdot(wX, g0 + q * 32); cbX = constdot(wX, be0 + q * 32);
    cgT = constdot(wT, g0 + q * 32); cbT = constdot(wT, be0 + q * 32);
  }
  const float bhx  = layer ? (bh1[j] + bx1[j]) : (bh0[j] + bx0[j]);
  const float btr  = layer ? bt1[j]  : bt0[j];
  const float taub = layer ? tau1[j] : tau0[j];
  const float gr   = layer ? g1[j]   : g0[j];
  const float ber  = layer ? be1[j]  : be0[j];

  // ---- stage x chunk 0 ----
  const float4* xg4 = (const float4*)(x + (size_t)b * (T_ * F_));
  {
    float4 v = xg4[t];
    uint32_t d0 = as_u32(pkf16(v.x, v.y)), d1 = as_u32(pkf16(v.z, v.w));
    *(uint2*)&xs[0][(t >> 4) * 32 + (t & 15) * 2] = make_uint2(d0, d1);
  }
  float hcp = 0.f;
  __syncthreads();

  // iter i: L0 -> hc0(i), L1 -> hc1(i-1); ONE barrier per iter
  for (int i = 0; i <= T_; ++i) {
    const int r  = i & 1;
    const int wb = r ^ 1;
    if ((i & 63) == 0) {
      int c = (i >> 6) + 1;
      if (c < 16) {
        float4 v = xg4[c * 1024 + t];
        uint32_t d0 = as_u32(pkf16(v.x, v.y)), d1 = as_u32(pkf16(v.z, v.w));
        *(uint2*)&xs[c & 1][(t >> 4) * 32 + (t & 15) * 2] = make_uint2(d0, d1);
      }
    }

    // ---- dots on published y (pre-normalization state) ----
    float pAy = 0.f, pXy = 0.f, pTy = 0.f;
    if (layer == 0) {
      h2 hv[16];
      LOADHV(hv, y0p[r] + q * 16)
      const uint4* xr = (const uint4*)&xs[(i >> 6) & 1][(i & 63) * 32 + q * 8];
      uint4 xa = xr[0], xb = xr[1];
      h2 xv[8] = { as_h2(xa.x), as_h2(xa.y), as_h2(xa.z), as_h2(xa.w),
                   as_h2(xb.x), as_h2(xb.y), as_h2(xb.z), as_h2(xb.w) };
      #pragma unroll
      for (int ii = 0; ii < 16; ++ii) pAy = fdot2(as_h2(wA[ii]), hv[ii], pAy);
      #pragma unroll
      for (int ii = 0; ii < 8; ++ii) {
        pXy = fdot2(as_h2(wX[ii]), xv[ii], pXy);
        pTy = fdot2(as_h2(wT[ii]), xv[ii], pTy);
      }
    } else {
      h2 hv[16], hg[16];
      LOADHV(hv, y1p[r] + q * 16)
      LOADHV(hg, y0p[r] + q * 16)
      #pragma unroll
      for (int ii = 0; ii < 16; ++ii) {
        pAy = fdot2(as_h2(wA[ii]), hv[ii], pAy);
        pXy = fdot2(as_h2(wX[ii]), hg[ii], pXy);
        pTy = fdot2(as_h2(wT[ii]), hg[ii], pTy);
      }
    }

    // ---- stats of consumed states (published last iter) ----
    float mu0s, rs0;
    {
      const float4* pf = (const float4*)(&part[r][0]);
      float4 p0 = pf[0], p1 = pf[1], p2 = pf[2], p3 = pf[3];
      float S  = p0.x + p0.z + p1.x + p1.z + p2.x + p2.z + p3.x + p3.z;
      float S2 = p0.y + p0.w + p1.y + p1.w + p2.y + p2.w + p3.y + p3.w;
      mu0s = S * (1.f / 128.f);
      rs0  = rsqrtf(S2 * (1.f / 128.f) - mu0s * mu0s + EPS_);
    }
    const bool f0 = (i >= 1), f1 = (i >= 2);

    float a, tp, hold;
    if (layer == 0) {
      float rA = f0 ? rs0 : 0.f;
      float z  = fmaf(rA, pAy, pXy);
      QSUM(z) QSUM(pTy)
      float cA = f0 ? fmaf(-mu0s * rA, cgA, cbA) : 0.f;
      a    = z + cA + bhx;
      tp   = pTy + btr;
      hold = f0 ? fmaf((hcp - mu0s) * rs0, gr, ber) : 0.f;
    } else {
      float mu1s, rs1;
      {
        const float4* pf = (const float4*)(&part[r][8]);
        float4 p0 = pf[0], p1 = pf[1], p2 = pf[2], p3 = pf[3];
        float S  = p0.x + p0.z + p1.x + p1.z + p2.x + p2.z + p3.x + p3.z;
        float S2 = p0.y + p0.w + p1.y + p1.w + p2.y + p2.w + p3.y + p3.w;
        mu1s = S * (1.f / 128.f);
        rs1  = rsqrtf(S2 * (1.f / 128.f) - mu1s * mu1s + EPS_);
      }
      float rA = f1 ? rs1 : 0.f, rX = f0 ? rs0 : 0.f;
      float z  = fmaf(rA, pAy, rX * pXy);
      float zT = rX * pTy;
      QSUM(z) QSUM(zT)
      float cA = f1 ? fmaf(-mu1s * rA, cgA, cbA) : 0.f;
      float cX = f0 ? fmaf(-mu0s * rX, cgX, cbX) : 0.f;
      float cT = f0 ? fmaf(-mu0s * rX, cgT, cbT) : 0.f;
      a    = z + cA + cX + bhx;
      tp   = zT + cT + btr;
      hold = f1 ? fmaf((hcp - mu1s) * rs1, gr, ber) : 0.f;
      hcp  = (f1 || i == 0) ? hcp : hcp;  // no-op; clarity
    }

    float f  = tanh_fast(a);
    float tv = taub + softplus_fast(tp);
    float hc = fmaf(f - hold, __builtin_amdgcn_rcpf(tv), hold);

    // ---- publish raw stats + y for next iter ----
    float s = hc, s2 = hc * hc;
    WRED(s) WRED(s2)
    if (l == 0) part[wb][w] = make_float2(s, s2);
    bool pubv = (layer == 0) || (i > 0);
    if (pubv && q == 0) ((__fp16*)(layer ? y1p[wb] : y0p[wb]))[j] = (__fp16)(gr * hc);
    hcp = hc;
    __syncthreads();                                       // the ONLY barrier
  }

  // epilogue: normalize hc1(T-1) with stats published at final iter
  if (layer == 1 && q == 0) {
    const float4* pf = (const float4*)(&part[(T_ + 1) & 1][8]);
    float4 p0 = pf[0], p1 = pf[1], p2 = pf[2], p3 = pf[3];
    float S  = p0.x + p0.z + p1.x + p1.z + p2.x + p2.z + p3.x + p3.z;
    float S2 = p0.y + p0.w + p1.y + p1.w + p2.y + p2.w + p3.y + p3.w;
    float mu1s = S * (1.f / 128.f);
    float rs1  = rsqrtf(S2 * (1.f / 128.f) - mu1s * mu1s + EPS_);
    out[b * H_ + j] = fmaf((hcp - mu1s) * rs1, gr, ber);   // hn1(T-1)
  }
}

extern "C" void kernel_launch(void* const* d_in, const int* in_sizes, int n_in,
                              void* d_out, int out_size, void* d_ws, size_t ws_size,
                              hipStream_t stream) {
  const float* x    = (const float*)d_in[0];
  const float* Wh0  = (const float*)d_in[1];
  const float* bh0  = (const float*)d_in[2];
  const float* Wx0  = (const float*)d_in[3];
  const float* bx0  = (const float*)d_in[4];
  const float* Wt0  = (const float*)d_in[5];
  const float* bt0  = (const float*)d_in[6];
  const float* tau0 = (const float*)d_in[7];
  const float* g0   = (const float*)d_in[8];
  const float* be0  = (const float*)d_in[9];
  const float* Wh1  = (const float*)d_in[10];
  const float* bh1  = (const float*)d_in[11];
  const float* Wx1  = (const float*)d_in[12];
  const float* bx1  = (const float*)d_in[13];
  const float* Wt1  = (const float*)d_in[14];
  const float* bt1  = (const float*)d_in[15];
  const float* tau1 = (const float*)d_in[16];
  const float* g1   = (const float*)d_in[17];
  const float* be1  = (const float*)d_in[18];
  float* out        = (float*)d_out;

  ltc_scan<<<B_, NT_, 0, stream>>>(x, Wh0, bh0, Wx0, bx0, Wt0, bt0, tau0, g0, be0,
                                   Wh1, bh1, Wx1, bx1, Wt1, bt1, tau1, g1, be1, out);
}